// Round 9
// baseline (330.411 us; speedup 1.0000x reference)
//
#include <hip/hip_runtime.h>
#include <cstdint>
#include <cstddef>

#define N_TOT 16384
#define DIM 512
#define EPS 1e-8f
#define LOG2E 1.44269504088896340736f
#define SCALE1 0x7F7F7F7Fu   // E8M0 = 127 -> 2^0 in every byte

typedef __attribute__((ext_vector_type(8))) int int8v;
typedef __attribute__((ext_vector_type(16))) float f32x16;

union FragU { int4 q[2]; int8v v; };

#define AS1 __attribute__((address_space(1)))
#define AS3 __attribute__((address_space(3)))

// ---------------------------------------------------------------------------
// fp8 frag-linear layout (per matrix, 8 MB):
//   chunk = grp32*8 + k64 (grp32 0..511, k64 0..7), 2048 B = two 1024 B halves.
//   lane l, elem j: byte = chunk*2048 + h*1024 + l*16 + j
//   row = grp32*32 + (l&31), k = k64*64 + (l>>5)*32 + h*16 + j
//   A and B share this (lane,elem)->k bijection => dot correct regardless of
//   HW k-order; uniform MX scales (2^0) make block mapping irrelevant.
// ws layout (bytes):
//   [0,        8388608)   imgF fp8
//   [8388608,  16777216)  txtF fp8
//   [16777216, 20971520)  rowpart float [64 bx][16384]
//   [20971520, 25165824)  colpart float [64 by][16384]
//   [25165824, 25296896)  lse float [2][16384]
//   [25296896, 25362432)  diag float [16384]
// ---------------------------------------------------------------------------

__global__ __launch_bounds__(256) void convert_kernel(
    const float* __restrict__ img, const float* __restrict__ txt,
    const float* __restrict__ scale_p,
    char* __restrict__ imgF, char* __restrict__ txtF) {
  const float fac = sqrtf((*scale_p) * LOG2E);  // exp(scale*S) = exp2(dot of scaled inputs)
  const float* src = blockIdx.y ? txt : img;
  char* dst = blockIdx.y ? txtF : imgF;
  int tm = blockIdx.x * 256 + threadIdx.x;      // 0..524287
  int c = tm >> 7;                               // chunk 0..4095... x2048 blocks
  int h = (tm >> 6) & 1;
  int l = tm & 63;
  int grp32 = c >> 3, k64 = c & 7;
  int row = grp32 * 32 + (l & 31);
  int kb = k64 * 64 + ((l >> 5) << 5) + h * 16;
  const float* p = src + (size_t)row * DIM + kb;
  float f[16];
#pragma unroll
  for (int e = 0; e < 16; ++e) f[e] = p[e] * fac;
  int4 w;
  int w0 = 0, w1 = 0, w2 = 0, w3 = 0;
  w0 = __builtin_amdgcn_cvt_pk_fp8_f32(f[0],  f[1],  w0, false);
  w0 = __builtin_amdgcn_cvt_pk_fp8_f32(f[2],  f[3],  w0, true);
  w1 = __builtin_amdgcn_cvt_pk_fp8_f32(f[4],  f[5],  w1, false);
  w1 = __builtin_amdgcn_cvt_pk_fp8_f32(f[6],  f[7],  w1, true);
  w2 = __builtin_amdgcn_cvt_pk_fp8_f32(f[8],  f[9],  w2, false);
  w2 = __builtin_amdgcn_cvt_pk_fp8_f32(f[10], f[11], w2, true);
  w3 = __builtin_amdgcn_cvt_pk_fp8_f32(f[12], f[13], w3, false);
  w3 = __builtin_amdgcn_cvt_pk_fp8_f32(f[14], f[15], w3, true);
  w.x = w0; w.y = w1; w.z = w2; w.w = w3;
  *reinterpret_cast<int4*>(dst + (size_t)c * 2048 + h * 1024 + l * 16) = w;
}

// ---------------------------------------------------------------------------
// Tiled fp8 GEMM + once-per-block exp epilogue. Tile 256x256, full K=512 in
// acc (4x2 f32x16 = 128 AGPR/lane). 8 waves (2 wr x 4 wc), wave owns 128x64.
// Both A and B staged in LDS per K64-step (dbuf), 12 ds_read_b128 + 8 MFMA
// per wave-step, one barrier per step, 8 steps. No long-lived operand regs.
// grid = 4096 blocks, XCD-chunked: each XCD gets 8 consecutive by-rows.
// ---------------------------------------------------------------------------
__global__ __launch_bounds__(512, 2) void gemm_lse_kernel(
    const char* __restrict__ imgF, const char* __restrict__ txtF,
    float* __restrict__ rowpart,   // [64 bx][16384]
    float* __restrict__ colpart) { // [64 by][16384]
  // bijective XCD chunk swizzle (4096 = 8 XCD * 512)
  const int wg  = blockIdx.x;
  const int sid = ((wg & 7) << 9) | (wg >> 3);
  const int by = sid >> 6, bx = sid & 63;
  const int wid = threadIdx.x >> 6;      // 0..7
  const int wr = wid >> 2, wc = wid & 3;
  const int l = threadIdx.x & 63;

  __shared__ int4 AsV[2][1024];          // 2 x 16KB A tile (256 rows x 64 K)
  __shared__ int4 BsV[2][1024];          // 2 x 16KB B tile (256 cols x 64 K)
  __shared__ float RowM[4][256];
  __shared__ float ColM[2][256];
  char* Asb = reinterpret_cast<char*>(&AsV[0][0]);
  char* Bsb = reinterpret_cast<char*>(&BsV[0][0]);

  // stage K-step kt into buffer b: wave wid stages its 2KB chunk of A and B
  auto stage = [&](int kt, int b) {
    const char* ga = imgF + ((size_t)((by * 8 + wid) * 8 + kt)) * 2048 + l * 16;
    const char* gb = txtF + ((size_t)((bx * 8 + wid) * 8 + kt)) * 2048 + l * 16;
    char* da = Asb + b * 16384 + wid * 2048;
    char* db = Bsb + b * 16384 + wid * 2048;
#pragma unroll
    for (int h = 0; h < 2; ++h) {
      __builtin_amdgcn_global_load_lds((const AS1 unsigned int*)(ga + h * 1024),
                                       (AS3 unsigned int*)(da + h * 1024), 16, 0, 0);
      __builtin_amdgcn_global_load_lds((const AS1 unsigned int*)(gb + h * 1024),
                                       (AS3 unsigned int*)(db + h * 1024), 16, 0, 0);
    }
  };

  stage(0, 0);

  f32x16 acc[4][2];
#pragma unroll
  for (int rg = 0; rg < 4; ++rg)
#pragma unroll
    for (int cg = 0; cg < 2; ++cg)
#pragma unroll
      for (int r = 0; r < 16; ++r) acc[rg][cg][r] = 0.f;

  __syncthreads();                       // stage(0) complete (drains vmcnt)

  const int NKT = 8;
  for (int kt = 0; kt < NKT; ++kt) {
    const int buf = kt & 1;
    if (kt + 1 < NKT) stage(kt + 1, buf ^ 1);
    const char* Ab = Asb + buf * 16384;
    const char* Bb = Bsb + buf * 16384;
    FragU fb0, fb1;
    fb0.q[0] = *reinterpret_cast<const int4*>(Bb + (wc * 2 + 0) * 2048 + l * 16);
    fb0.q[1] = *reinterpret_cast<const int4*>(Bb + (wc * 2 + 0) * 2048 + 1024 + l * 16);
    fb1.q[0] = *reinterpret_cast<const int4*>(Bb + (wc * 2 + 1) * 2048 + l * 16);
    fb1.q[1] = *reinterpret_cast<const int4*>(Bb + (wc * 2 + 1) * 2048 + 1024 + l * 16);
    __builtin_amdgcn_s_setprio(1);
#pragma unroll
    for (int rg = 0; rg < 4; ++rg) {
      FragU fa;
      fa.q[0] = *reinterpret_cast<const int4*>(Ab + (wr * 4 + rg) * 2048 + l * 16);
      fa.q[1] = *reinterpret_cast<const int4*>(Ab + (wr * 4 + rg) * 2048 + 1024 + l * 16);
      acc[rg][0] = __builtin_amdgcn_mfma_scale_f32_32x32x64_f8f6f4(
          fa.v, fb0.v, acc[rg][0], 0, 0, 0, SCALE1, 0, SCALE1);
      acc[rg][1] = __builtin_amdgcn_mfma_scale_f32_32x32x64_f8f6f4(
          fa.v, fb1.v, acc[rg][1], 0, 0, 0, SCALE1, 0, SCALE1);
    }
    __builtin_amdgcn_s_setprio(0);
    __syncthreads();                     // dbuf WAR + next-stage vmcnt drain
  }

  // ---- epilogue: exp once, row/col partial sums, in-block merges ----
  // C layout per 32x32: col = cg*32 + (l&31), row = (r&3) + 8*(r>>2) + 4*(l>>5)
  float cs0 = 0.f, cs1 = 0.f;
#pragma unroll
  for (int rg = 0; rg < 4; ++rg) {
    float rs[16];
#pragma unroll
    for (int r = 0; r < 16; ++r) {
      float e0 = exp2f(acc[rg][0][r]);
      float e1 = exp2f(acc[rg][1][r]);
      rs[r] = e0 + e1; cs0 += e0; cs1 += e1;
    }
#pragma unroll
    for (int r = 0; r < 16; ++r) {
#pragma unroll
      for (int off = 1; off < 32; off <<= 1) rs[r] += __shfl_xor(rs[r], off, 64);
    }
    if ((l & 31) == 0) {
      int rbase = wr * 128 + rg * 32 + ((l >> 5) << 2);
#pragma unroll
      for (int r = 0; r < 16; ++r)
        RowM[wc][rbase + (r & 3) + ((r >> 2) << 3)] = rs[r];
    }
  }
  cs0 += __shfl_xor(cs0, 32, 64);        // merge hi/lo row-halves per col
  cs1 += __shfl_xor(cs1, 32, 64);
  if (l < 32) {
    ColM[wr][wc * 64 + l] = cs0;
    ColM[wr][wc * 64 + 32 + l] = cs1;
  }
  __syncthreads();
  if (threadIdx.x < 256) {
    int t = threadIdx.x;
    rowpart[(size_t)bx * N_TOT + by * 256 + t] =
        RowM[0][t] + RowM[1][t] + RowM[2][t] + RowM[3][t];
    colpart[(size_t)by * N_TOT + bx * 256 + t] = ColM[0][t] + ColM[1][t];
  }
}

// exact fp32 diagonal: one wave per row
__global__ __launch_bounds__(256) void diag_kernel(
    const float* __restrict__ img, const float* __restrict__ txt,
    float* __restrict__ diag) {
  int wid = threadIdx.x >> 6, l = threadIdx.x & 63;
  int row = blockIdx.x * 4 + wid;
  const float4* a = reinterpret_cast<const float4*>(img + (size_t)row * DIM) + l * 2;
  const float4* b = reinterpret_cast<const float4*>(txt + (size_t)row * DIM) + l * 2;
  float s = 0.f;
#pragma unroll
  for (int j = 0; j < 2; ++j) {
    float4 x = a[j], y = b[j];
    s += x.x * y.x + x.y * y.y + x.z * y.z + x.w * y.w;
  }
#pragma unroll
  for (int off = 32; off > 0; off >>= 1) s += __shfl_down(s, off, 64);
  if (l == 0) diag[row] = s;
}

// sum 64 partials per row (y=0) / per col (y=1), take log
__global__ __launch_bounds__(256) void reduce_kernel(
    const float* __restrict__ rowpart, const float* __restrict__ colpart,
    float* __restrict__ lse) {
  int i = blockIdx.x * 256 + threadIdx.x;
  const float* p = blockIdx.y ? colpart : rowpart;
  float s = 0.f;
#pragma unroll 8
  for (int g = 0; g < 64; ++g) s += p[(size_t)g * N_TOT + i];
  lse[(size_t)blockIdx.y * N_TOT + i] = __logf(s + EPS);
}

// final: mean over rows+cols of lse, minus scale*mean(diag)
__global__ __launch_bounds__(256) void final_kernel(
    const float* __restrict__ lse, const float* __restrict__ diag,
    const float* __restrict__ scale_p, float* __restrict__ out) {
  int t = threadIdx.x;
  float sden = 0.f, sdiag = 0.f;
  for (int i = t; i < N_TOT; i += 256) {
    sden += lse[i] + lse[N_TOT + i];
    sdiag += diag[i];
  }
  __shared__ float rA[256], rB[256];
  rA[t] = sden; rB[t] = sdiag;
  __syncthreads();
  for (int s2 = 128; s2 > 0; s2 >>= 1) {
    if (t < s2) { rA[t] += rA[t + s2]; rB[t] += rB[t + s2]; }
    __syncthreads();
  }
  if (t == 0)
    out[0] = 0.5f * rA[0] / (float)N_TOT - (*scale_p) * rB[0] / (float)N_TOT;
}

extern "C" void kernel_launch(void* const* d_in, const int* in_sizes, int n_in,
                              void* d_out, int out_size, void* d_ws, size_t ws_size,
                              hipStream_t stream) {
  const float* img     = (const float*)d_in[0];
  const float* txt     = (const float*)d_in[1];
  const float* scale_p = (const float*)d_in[2];
  float* out = (float*)d_out;
  char* ws = (char*)d_ws;   // needs ~25.4 MB
  char*  imgF    = ws;
  char*  txtF    = ws + (size_t)8388608;
  float* rowpart = (float*)(ws + (size_t)16777216);
  float* colpart = (float*)(ws + (size_t)20971520);
  float* lse     = (float*)(ws + (size_t)25165824);
  float* diag    = (float*)(ws + (size_t)25296896);

  convert_kernel<<<dim3(2048, 2, 1), 256, 0, stream>>>(img, txt, scale_p, imgF, txtF);
  gemm_lse_kernel<<<dim3(4096, 1, 1), 512, 0, stream>>>(imgF, txtF, rowpart, colpart);
  diag_kernel<<<dim3(4096, 1, 1), 256, 0, stream>>>(img, txt, diag);
  reduce_kernel<<<dim3(64, 2, 1), 256, 0, stream>>>(rowpart, colpart, lse);
  final_kernel<<<dim3(1, 1, 1), 256, 0, stream>>>(lse, diag, scale_p, out);
}

// Round 11
// 262.903 us; speedup vs baseline: 1.2568x; 1.2568x over previous
//
#include <hip/hip_runtime.h>
#include <cstdint>
#include <cstddef>

#define N_TOT 16384
#define DIM 512
#define EPS 1e-8f
#define LOG2E 1.44269504088896340736f
#define SCALE1 0x7F7F7F7Fu   // E8M0 = 127 -> 2^0 in every byte

typedef __attribute__((ext_vector_type(8))) int int8v;
typedef __attribute__((ext_vector_type(16))) float f32x16;

union FragU { int4 q[2]; int8v v; };

#define AS1 __attribute__((address_space(1)))
#define AS3 __attribute__((address_space(3)))

// ---------------------------------------------------------------------------
// fp8 frag-linear layout (per matrix, 8 MB):
//   chunk = grp32*8 + k64 (grp32 0..511, k64 0..7), 2048 B = two 1024 B halves.
//   lane l, elem j: byte = chunk*2048 + h*1024 + l*16 + j
//   row = grp32*32 + (l&31), k = k64*64 + (l>>5)*32 + h*16 + j
//   A and B share this (lane,elem)->k bijection => dot correct regardless of
//   HW k-order; uniform MX scales (2^0) make block mapping irrelevant.
//   A block's 128 rows x 512 K = 32 consecutive chunks = contiguous 64 KB.
//   8192 cols (one csplit) = 256 grp32 = 4,194,304 B  <-- r10 bug: used 8 MB.
// ws layout (bytes):
//   [0,        8388608)   imgF fp8
//   [8388608,  16777216)  txtF fp8
//   [16777216, 25165824)  colpart float [128 rb][16384]
//   [25165824, 25427968)  rowpart float [4 (csplit*2+cg)][16384]
//   [25427968, 25559040)  lse float [2][16384]
//   [25559040, 25624576)  diag float [16384]
// ---------------------------------------------------------------------------

__global__ __launch_bounds__(256) void convert_kernel(
    const float* __restrict__ img, const float* __restrict__ txt,
    const float* __restrict__ scale_p,
    char* __restrict__ imgF, char* __restrict__ txtF) {
  const float fac = sqrtf((*scale_p) * LOG2E);  // exp(scale*S) = exp2(dot of scaled inputs)
  const float* src = blockIdx.y ? txt : img;
  char* dst = blockIdx.y ? txtF : imgF;
  int tm = blockIdx.x * 256 + threadIdx.x;      // 0..524287
  int c = tm >> 7;                               // chunk 0..4095
  int h = (tm >> 6) & 1;
  int l = tm & 63;
  int grp32 = c >> 3, k64 = c & 7;
  int row = grp32 * 32 + (l & 31);
  int kb = k64 * 64 + ((l >> 5) << 5) + h * 16;
  const float* p = src + (size_t)row * DIM + kb;
  float f[16];
#pragma unroll
  for (int e = 0; e < 16; ++e) f[e] = p[e] * fac;
  int4 w;
  int w0 = 0, w1 = 0, w2 = 0, w3 = 0;
  w0 = __builtin_amdgcn_cvt_pk_fp8_f32(f[0],  f[1],  w0, false);
  w0 = __builtin_amdgcn_cvt_pk_fp8_f32(f[2],  f[3],  w0, true);
  w1 = __builtin_amdgcn_cvt_pk_fp8_f32(f[4],  f[5],  w1, false);
  w1 = __builtin_amdgcn_cvt_pk_fp8_f32(f[6],  f[7],  w1, true);
  w2 = __builtin_amdgcn_cvt_pk_fp8_f32(f[8],  f[9],  w2, false);
  w2 = __builtin_amdgcn_cvt_pk_fp8_f32(f[10], f[11], w2, true);
  w3 = __builtin_amdgcn_cvt_pk_fp8_f32(f[12], f[13], w3, false);
  w3 = __builtin_amdgcn_cvt_pk_fp8_f32(f[14], f[15], w3, true);
  w.x = w0; w.y = w1; w.z = w2; w.w = w3;
  *reinterpret_cast<int4*>(dst + (size_t)c * 2048 + h * 1024 + l * 16) = w;
}

// ---------------------------------------------------------------------------
// Fused fp8 GEMM + LSE partials. Block = 128 rows x full K=512: A tile 64 KB
// staged in LDS ONCE; sweeps 128 B-panels (64 cols x 512 K = 32 KB, dbuf).
// 8 waves = 4 rg x 2 cg; wave owns one 32x32 output tile per panel, K fully
// accumulated in one f32x16. One barrier per panel (~1100 cyc MFMA between).
// Rowsums live in VGPRs across the whole sweep; colsums merged via parity-
// double-buffered ColM LDS. grid = 256 = 1/CU, XCD-chunk-swizzled.
// ---------------------------------------------------------------------------
__global__ __launch_bounds__(512, 2) void gemm_lse_kernel(
    const char* __restrict__ imgF, const char* __restrict__ txtF,
    float* __restrict__ rowpart,   // [4][16384]
    float* __restrict__ colpart) { // [128 rb][16384]
  // swizzle: XCD x gets 32 consecutive blocks: same csplit, contiguous rb
  const int wg = blockIdx.x;                 // 0..255
  const int sid = ((wg & 7) << 5) | (wg >> 3);
  const int csplit = sid >> 7;               // 0..1
  const int rb     = sid & 127;              // 0..127 : 128-row block
  const int wid = threadIdx.x >> 6;          // 0..7
  const int rg = wid >> 1, cg = wid & 1;
  const int l = threadIdx.x & 63;

  __shared__ int4 LDS[(65536 + 2 * 32768) / 16];   // A 64KB | B dbuf 2x32KB
  __shared__ float ColM[2][4][64];
  char* Asb = reinterpret_cast<char*>(&LDS[0]);
  char* Bsb = Asb + 65536;

  // --- stage A once: contiguous 64 KB (chunks rb*32 .. rb*32+32) ---
  {
    const char* ga = imgF + (size_t)rb * 65536 + wid * 8192 + l * 16;
    char* da = Asb + wid * 8192;
#pragma unroll
    for (int i = 0; i < 8; ++i)
      __builtin_amdgcn_global_load_lds((const AS1 unsigned int*)(ga + i * 1024),
                                       (AS3 unsigned int*)(da + i * 1024), 16, 0, 0);
  }
  // --- stage B panel 0 into buf 0: contiguous 32 KB ---
  const char* Bbase = txtF + (size_t)csplit * 4194304;   // this csplit's 8192 cols (FIXED)
  {
    const char* gb = Bbase + wid * 4096 + l * 16;
#pragma unroll
    for (int i = 0; i < 4; ++i)
      __builtin_amdgcn_global_load_lds((const AS1 unsigned int*)(gb + i * 1024),
                                       (AS3 unsigned int*)(Bsb + wid * 4096 + i * 1024), 16, 0, 0);
  }

  float rowsum[16];
#pragma unroll
  for (int r = 0; r < 16; ++r) rowsum[r] = 0.f;

  __syncthreads();                            // A + panel0 staged (vmcnt drained)

  const int NP = 128;                         // 64-col panels per block
  for (int p = 0; p < NP; ++p) {
    const int buf = p & 1;
    if (p + 1 < NP) {                         // stage next panel into other buf
      const char* gb = Bbase + (size_t)(p + 1) * 32768 + wid * 4096 + l * 16;
      char* db = Bsb + (buf ^ 1) * 32768 + wid * 4096;
#pragma unroll
      for (int i = 0; i < 4; ++i)
        __builtin_amdgcn_global_load_lds((const AS1 unsigned int*)(gb + i * 1024),
                                         (AS3 unsigned int*)(db + i * 1024), 16, 0, 0);
    }
    const char* Ab = Asb + (rg * 8) * 2048 + l * 16;
    const char* Bb = Bsb + buf * 32768 + (cg * 8) * 2048 + l * 16;
    f32x16 acc;
#pragma unroll
    for (int r = 0; r < 16; ++r) acc[r] = 0.f;
    __builtin_amdgcn_s_setprio(1);
#pragma unroll
    for (int k = 0; k < 8; ++k) {             // full K=512 into one acc
      FragU fa, fb;
      fa.q[0] = *reinterpret_cast<const int4*>(Ab + k * 2048);
      fa.q[1] = *reinterpret_cast<const int4*>(Ab + k * 2048 + 1024);
      fb.q[0] = *reinterpret_cast<const int4*>(Bb + k * 2048);
      fb.q[1] = *reinterpret_cast<const int4*>(Bb + k * 2048 + 1024);
      acc = __builtin_amdgcn_mfma_scale_f32_32x32x64_f8f6f4(
          fa.v, fb.v, acc, 0, 0, 0, SCALE1, 0, SCALE1);
    }
    __builtin_amdgcn_s_setprio(0);
    // tail: 16 exp2; each lane's 16 values share ONE column (col = cg*32+(l&31))
    float colp = 0.f;
#pragma unroll
    for (int r = 0; r < 16; ++r) {
      float e = exp2f(acc[r]);
      rowsum[r] += e;                         // per-lane row partial (accumulated over panels)
      colp += e;
    }
    colp += __shfl_xor(colp, 32, 64);         // merge hi/lo 32-row halves
    if (l < 32) ColM[buf][rg][cg * 32 + l] = colp;
    __syncthreads();                          // dbuf WAR + next-stage vmcnt + ColM visible
    if (threadIdx.x < 64) {                   // cross-rg col merge + flush (64 cols)
      int c = threadIdx.x;
      float s = ColM[buf][0][c] + ColM[buf][1][c] + ColM[buf][2][c] + ColM[buf][3][c];
      colpart[(size_t)rb * N_TOT + (size_t)csplit * 8192 + p * 64 + c] = s;
    }
  }

  // row partials: butterfly over the 32 col-lanes (within each hi/lo half)
#pragma unroll
  for (int r = 0; r < 16; ++r) {
#pragma unroll
    for (int off = 1; off < 32; off <<= 1) rowsum[r] += __shfl_xor(rowsum[r], off, 64);
  }
  if ((l & 31) == 0) {
    int hi = l >> 5;
#pragma unroll
    for (int r = 0; r < 16; ++r) {
      int row = rb * 128 + rg * 32 + (r & 3) + ((r >> 2) << 3) + 4 * hi;
      rowpart[(size_t)(csplit * 2 + cg) * N_TOT + row] = rowsum[r];
    }
  }
}

// exact fp32 diagonal: one wave per row
__global__ __launch_bounds__(256) void diag_kernel(
    const float* __restrict__ img, const float* __restrict__ txt,
    float* __restrict__ diag) {
  int wid = threadIdx.x >> 6, l = threadIdx.x & 63;
  int row = blockIdx.x * 4 + wid;
  const float4* a = reinterpret_cast<const float4*>(img + (size_t)row * DIM) + l * 2;
  const float4* b = reinterpret_cast<const float4*>(txt + (size_t)row * DIM) + l * 2;
  float s = 0.f;
#pragma unroll
  for (int j = 0; j < 2; ++j) {
    float4 x = a[j], y = b[j];
    s += x.x * y.x + x.y * y.y + x.z * y.z + x.w * y.w;
  }
#pragma unroll
  for (int off = 32; off > 0; off >>= 1) s += __shfl_down(s, off, 64);
  if (l == 0) diag[row] = s;
}

// y=0: row LSE (sum 4 slices); y=1: col LSE (sum 128 slices)
__global__ __launch_bounds__(256) void reduce_kernel(
    const float* __restrict__ rowpart, const float* __restrict__ colpart,
    float* __restrict__ lse) {
  int i = blockIdx.x * 256 + threadIdx.x;
  float s = 0.f;
  if (blockIdx.y == 0) {
#pragma unroll
    for (int g = 0; g < 4; ++g) s += rowpart[(size_t)g * N_TOT + i];
  } else {
#pragma unroll 8
    for (int g = 0; g < 128; ++g) s += colpart[(size_t)g * N_TOT + i];
  }
  lse[(size_t)blockIdx.y * N_TOT + i] = __logf(s + EPS);
}

// final: mean over rows+cols of lse, minus scale*mean(diag)
__global__ __launch_bounds__(256) void final_kernel(
    const float* __restrict__ lse, const float* __restrict__ diag,
    const float* __restrict__ scale_p, float* __restrict__ out) {
  int t = threadIdx.x;
  float sden = 0.f, sdiag = 0.f;
  for (int i = t; i < N_TOT; i += 256) {
    sden += lse[i] + lse[N_TOT + i];
    sdiag += diag[i];
  }
  __shared__ float rA[256], rB[256];
  rA[t] = sden; rB[t] = sdiag;
  __syncthreads();
  for (int s2 = 128; s2 > 0; s2 >>= 1) {
    if (t < s2) { rA[t] += rA[t + s2]; rB[t] += rB[t + s2]; }
    __syncthreads();
  }
  if (t == 0)
    out[0] = 0.5f * rA[0] / (float)N_TOT - (*scale_p) * rB[0] / (float)N_TOT;
}

extern "C" void kernel_launch(void* const* d_in, const int* in_sizes, int n_in,
                              void* d_out, int out_size, void* d_ws, size_t ws_size,
                              hipStream_t stream) {
  const float* img     = (const float*)d_in[0];
  const float* txt     = (const float*)d_in[1];
  const float* scale_p = (const float*)d_in[2];
  float* out = (float*)d_out;
  char* ws = (char*)d_ws;   // needs ~24.5 MB
  char*  imgF    = ws;
  char*  txtF    = ws + (size_t)8388608;
  float* colpart = (float*)(ws + (size_t)16777216);
  float* rowpart = (float*)(ws + (size_t)25165824);
  float* lse     = (float*)(ws + (size_t)25427968);
  float* diag    = (float*)(ws + (size_t)25559040);

  convert_kernel<<<dim3(2048, 2, 1), 256, 0, stream>>>(img, txt, scale_p, imgF, txtF);
  gemm_lse_kernel<<<dim3(256, 1, 1), 512, 0, stream>>>(imgF, txtF, rowpart, colpart);
  diag_kernel<<<dim3(4096, 1, 1), 256, 0, stream>>>(img, txt, diag);
  reduce_kernel<<<dim3(64, 2, 1), 256, 0, stream>>>(rowpart, colpart, lse);
  final_kernel<<<dim3(1, 1, 1), 256, 0, stream>>>(lse, diag, scale_p, out);
}

// Round 12
// 234.340 us; speedup vs baseline: 1.4100x; 1.1219x over previous
//
#include <hip/hip_runtime.h>
#include <cstdint>
#include <cstddef>

#define N_TOT 16384
#define DIM 512
#define EPS 1e-8f
#define LOG2E 1.44269504088896340736f
#define SCALE1 0x7F7F7F7Fu   // E8M0 = 127 -> 2^0 in every byte

typedef __attribute__((ext_vector_type(8))) int int8v;
typedef __attribute__((ext_vector_type(16))) float f32x16;

union FragU { int4 q[2]; int8v v; };

#define AS1 __attribute__((address_space(1)))
#define AS3 __attribute__((address_space(3)))

// ---------------------------------------------------------------------------
// fp8 frag-linear layout (per matrix, 8 MB):
//   chunk = grp32*8 + k64 (grp32 0..511, k64 0..7), 2048 B = two 1024 B halves.
//   lane l, elem j: byte = chunk*2048 + h*1024 + l*16 + j
//   row = grp32*32 + (l&31), k = k64*64 + (l>>5)*32 + h*16 + j
//   A and B share this (lane,elem)->k bijection => dot correct regardless of
//   HW k-order; uniform MX scales (2^0) make block mapping irrelevant.
// ws layout (bytes):
//   [0,        8388608)   imgF fp8
//   [8388608,  16777216)  txtF fp8
//   [16777216, 25165824)  colpart float [128 (rb*2+wr)][16384]
//   [25165824, 25427968)  rowpart float [4 csplit][16384]
//   [25427968, 25559040)  lse float [2][16384]
//   [25559040, 25624576)  diag float [16384]
// ---------------------------------------------------------------------------

__global__ __launch_bounds__(256) void convert_kernel(
    const float* __restrict__ img, const float* __restrict__ txt,
    const float* __restrict__ scale_p,
    char* __restrict__ imgF, char* __restrict__ txtF) {
  const float fac = sqrtf((*scale_p) * LOG2E);  // exp(scale*S) = exp2(dot of scaled inputs)
  const float* src = blockIdx.y ? txt : img;
  char* dst = blockIdx.y ? txtF : imgF;
  int tm = blockIdx.x * 256 + threadIdx.x;      // 0..524287
  int c = tm >> 7;                               // chunk 0..4095
  int h = (tm >> 6) & 1;
  int l = tm & 63;
  int grp32 = c >> 3, k64 = c & 7;
  int row = grp32 * 32 + (l & 31);
  int kb = k64 * 64 + ((l >> 5) << 5) + h * 16;
  const float* p = src + (size_t)row * DIM + kb;
  float f[16];
#pragma unroll
  for (int e = 0; e < 16; ++e) f[e] = p[e] * fac;
  int4 w;
  int w0 = 0, w1 = 0, w2 = 0, w3 = 0;
  w0 = __builtin_amdgcn_cvt_pk_fp8_f32(f[0],  f[1],  w0, false);
  w0 = __builtin_amdgcn_cvt_pk_fp8_f32(f[2],  f[3],  w0, true);
  w1 = __builtin_amdgcn_cvt_pk_fp8_f32(f[4],  f[5],  w1, false);
  w1 = __builtin_amdgcn_cvt_pk_fp8_f32(f[6],  f[7],  w1, true);
  w2 = __builtin_amdgcn_cvt_pk_fp8_f32(f[8],  f[9],  w2, false);
  w2 = __builtin_amdgcn_cvt_pk_fp8_f32(f[10], f[11], w2, true);
  w3 = __builtin_amdgcn_cvt_pk_fp8_f32(f[12], f[13], w3, false);
  w3 = __builtin_amdgcn_cvt_pk_fp8_f32(f[14], f[15], w3, true);
  w.x = w0; w.y = w1; w.z = w2; w.w = w3;
  *reinterpret_cast<int4*>(dst + (size_t)c * 2048 + h * 1024 + l * 16) = w;
}

// ---------------------------------------------------------------------------
// Fused fp8 GEMM + LSE partials, register-blocked Rm=4 x Rn=2.
// Block = 256 rows x 4096 cols (one csplit), long-lived: 16 panels of 256
// cols, 8 k64-chunks each. Per step: stage next A+B chunk (2x16KB dbuf),
// 12 ds_read_b128 : 8 MFMA per wave (LDS 1152 cyc ~ MFMA 1088 cyc per CU).
// 8 waves (2 wr x 4 wc), wave tile 128x64, acc[4][2] f32x16 = 128 AGPR,
// rowsum[4][16] persists in VGPR. grid = 256 = 1/CU, XCD-chunk-swizzled.
// ---------------------------------------------------------------------------
__global__ __launch_bounds__(512, 2) void gemm_lse_kernel(
    const char* __restrict__ imgF, const char* __restrict__ txtF,
    float* __restrict__ rowpart,   // [4][16384]
    float* __restrict__ colpart) { // [128][16384]
  const int wg = blockIdx.x;                 // 0..255
  const int sid = ((wg & 7) << 5) | (wg >> 3);   // XCD gets 32 consecutive sids
  const int rb     = sid >> 2;               // 0..63 : 256-row block
  const int csplit = sid & 3;                // 0..3  : 4096-col slice
  const int wid = threadIdx.x >> 6;          // 0..7
  const int wr = wid >> 2, wc = wid & 3;
  const int l = threadIdx.x & 63;

  __shared__ int4 StageV[2][2048];           // [buf][A 16KB | B 16KB]
  __shared__ float RowM[4][256];
  char* Sb = reinterpret_cast<char*>(&StageV[0][0]);

  // stage step s = p*8+k into buf b: wave wid stages A gl=wid + B gl=wid
  auto stage = [&](int s, int b) {
    const int p = s >> 3, k = s & 7;
    const char* ga = imgF + ((size_t)((rb * 8 + wid) * 8 + k)) * 2048 + l * 16;
    const char* gb = txtF + ((size_t)((csplit * 128 + p * 8 + wid) * 8 + k)) * 2048 + l * 16;
    char* da = Sb + b * 32768 + wid * 2048;
    char* db = Sb + b * 32768 + 16384 + wid * 2048;
#pragma unroll
    for (int h = 0; h < 2; ++h) {
      __builtin_amdgcn_global_load_lds((const AS1 unsigned int*)(ga + h * 1024),
                                       (AS3 unsigned int*)(da + h * 1024), 16, 0, 0);
      __builtin_amdgcn_global_load_lds((const AS1 unsigned int*)(gb + h * 1024),
                                       (AS3 unsigned int*)(db + h * 1024), 16, 0, 0);
    }
  };

  float rowsum[4][16];
#pragma unroll
  for (int rg = 0; rg < 4; ++rg)
#pragma unroll
    for (int r = 0; r < 16; ++r) rowsum[rg][r] = 0.f;

  stage(0, 0);
  __syncthreads();                           // step 0 staged (vmcnt drained)

  for (int p = 0; p < 16; ++p) {
    f32x16 acc[4][2];
#pragma unroll
    for (int rg = 0; rg < 4; ++rg)
#pragma unroll
      for (int cg = 0; cg < 2; ++cg)
#pragma unroll
        for (int r = 0; r < 16; ++r) acc[rg][cg][r] = 0.f;

    for (int k = 0; k < 8; ++k) {
      const int s = p * 8 + k, buf = s & 1;
      if (s + 1 < 128) stage(s + 1, buf ^ 1);
      const char* Ab = Sb + buf * 32768 + (wr * 4) * 2048 + l * 16;
      const char* Bb = Sb + buf * 32768 + 16384 + (wc * 2) * 2048 + l * 16;
      FragU fb0, fb1;
      fb0.q[0] = *reinterpret_cast<const int4*>(Bb);
      fb0.q[1] = *reinterpret_cast<const int4*>(Bb + 1024);
      fb1.q[0] = *reinterpret_cast<const int4*>(Bb + 2048);
      fb1.q[1] = *reinterpret_cast<const int4*>(Bb + 3072);
      __builtin_amdgcn_s_setprio(1);
#pragma unroll
      for (int rg = 0; rg < 4; ++rg) {
        FragU fa;
        fa.q[0] = *reinterpret_cast<const int4*>(Ab + rg * 2048);
        fa.q[1] = *reinterpret_cast<const int4*>(Ab + rg * 2048 + 1024);
        acc[rg][0] = __builtin_amdgcn_mfma_scale_f32_32x32x64_f8f6f4(
            fa.v, fb0.v, acc[rg][0], 0, 0, 0, SCALE1, 0, SCALE1);
        acc[rg][1] = __builtin_amdgcn_mfma_scale_f32_32x32x64_f8f6f4(
            fa.v, fb1.v, acc[rg][1], 0, 0, 0, SCALE1, 0, SCALE1);
      }
      __builtin_amdgcn_s_setprio(0);
      __syncthreads();                       // dbuf WAR + stage vmcnt drain
    }
    // panel tail: exp once per logit; col-partials straight to global
    float colp0 = 0.f, colp1 = 0.f;
#pragma unroll
    for (int rg = 0; rg < 4; ++rg)
#pragma unroll
      for (int r = 0; r < 16; ++r) {
        float e0 = exp2f(acc[rg][0][r]);
        float e1 = exp2f(acc[rg][1][r]);
        rowsum[rg][r] += e0 + e1;
        colp0 += e0; colp1 += e1;
      }
    colp0 += __shfl_xor(colp0, 32, 64);      // merge hi/lo row-halves
    colp1 += __shfl_xor(colp1, 32, 64);
    if (l < 32) {
      size_t base = (size_t)(rb * 2 + wr) * N_TOT + csplit * 4096 + p * 256 + wc * 64;
      colpart[base + l] = colp0;
      colpart[base + 32 + l] = colp1;
    }
  }

  // block-end: merge rowsums across the 4 wc-waves via LDS
#pragma unroll
  for (int rg = 0; rg < 4; ++rg)
#pragma unroll
    for (int r = 0; r < 16; ++r) {
#pragma unroll
      for (int off = 1; off < 32; off <<= 1)
        rowsum[rg][r] += __shfl_xor(rowsum[rg][r], off, 64);
    }
  if ((l & 31) == 0) {
    int hi = l >> 5;
#pragma unroll
    for (int rg = 0; rg < 4; ++rg)
#pragma unroll
      for (int r = 0; r < 16; ++r)
        RowM[wc][wr * 128 + rg * 32 + (r & 3) + ((r >> 2) << 3) + 4 * hi] = rowsum[rg][r];
  }
  __syncthreads();
  if (threadIdx.x < 256) {
    int t = threadIdx.x;
    rowpart[(size_t)csplit * N_TOT + rb * 256 + t] =
        RowM[0][t] + RowM[1][t] + RowM[2][t] + RowM[3][t];
  }
}

// exact fp32 diagonal: one wave per row
__global__ __launch_bounds__(256) void diag_kernel(
    const float* __restrict__ img, const float* __restrict__ txt,
    float* __restrict__ diag) {
  int wid = threadIdx.x >> 6, l = threadIdx.x & 63;
  int row = blockIdx.x * 4 + wid;
  const float4* a = reinterpret_cast<const float4*>(img + (size_t)row * DIM) + l * 2;
  const float4* b = reinterpret_cast<const float4*>(txt + (size_t)row * DIM) + l * 2;
  float s = 0.f;
#pragma unroll
  for (int j = 0; j < 2; ++j) {
    float4 x = a[j], y = b[j];
    s += x.x * y.x + x.y * y.y + x.z * y.z + x.w * y.w;
  }
#pragma unroll
  for (int off = 32; off > 0; off >>= 1) s += __shfl_down(s, off, 64);
  if (l == 0) diag[row] = s;
}

// y=0: row LSE (sum 4 slices); y=1: col LSE (sum 128 slices)
__global__ __launch_bounds__(256) void reduce_kernel(
    const float* __restrict__ rowpart, const float* __restrict__ colpart,
    float* __restrict__ lse) {
  int i = blockIdx.x * 256 + threadIdx.x;
  float s = 0.f;
  if (blockIdx.y == 0) {
#pragma unroll
    for (int g = 0; g < 4; ++g) s += rowpart[(size_t)g * N_TOT + i];
  } else {
#pragma unroll 8
    for (int g = 0; g < 128; ++g) s += colpart[(size_t)g * N_TOT + i];
  }
  lse[(size_t)blockIdx.y * N_TOT + i] = __logf(s + EPS);
}

// final: mean over rows+cols of lse, minus scale*mean(diag)
__global__ __launch_bounds__(256) void final_kernel(
    const float* __restrict__ lse, const float* __restrict__ diag,
    const float* __restrict__ scale_p, float* __restrict__ out) {
  int t = threadIdx.x;
  float sden = 0.f, sdiag = 0.f;
  for (int i = t; i < N_TOT; i += 256) {
    sden += lse[i] + lse[N_TOT + i];
    sdiag += diag[i];
  }
  __shared__ float rA[256], rB[256];
  rA[t] = sden; rB[t] = sdiag;
  __syncthreads();
  for (int s2 = 128; s2 > 0; s2 >>= 1) {
    if (t < s2) { rA[t] += rA[t + s2]; rB[t] += rB[t + s2]; }
    __syncthreads();
  }
  if (t == 0)
    out[0] = 0.5f * rA[0] / (float)N_TOT - (*scale_p) * rB[0] / (float)N_TOT;
}

extern "C" void kernel_launch(void* const* d_in, const int* in_sizes, int n_in,
                              void* d_out, int out_size, void* d_ws, size_t ws_size,
                              hipStream_t stream) {
  const float* img     = (const float*)d_in[0];
  const float* txt     = (const float*)d_in[1];
  const float* scale_p = (const float*)d_in[2];
  float* out = (float*)d_out;
  char* ws = (char*)d_ws;   // needs ~24.5 MB
  char*  imgF    = ws;
  char*  txtF    = ws + (size_t)8388608;
  float* colpart = (float*)(ws + (size_t)16777216);
  float* rowpart = (float*)(ws + (size_t)25165824);
  float* lse     = (float*)(ws + (size_t)25427968);
  float* diag    = (float*)(ws + (size_t)25559040);

  convert_kernel<<<dim3(2048, 2, 1), 256, 0, stream>>>(img, txt, scale_p, imgF, txtF);
  gemm_lse_kernel<<<dim3(256, 1, 1), 512, 0, stream>>>(imgF, txtF, rowpart, colpart);
  diag_kernel<<<dim3(4096, 1, 1), 256, 0, stream>>>(img, txt, diag);
  reduce_kernel<<<dim3(64, 2, 1), 256, 0, stream>>>(rowpart, colpart, lse);
  final_kernel<<<dim3(1, 1, 1), 256, 0, stream>>>(lse, diag, scale_p, out);
}